// Round 2
// baseline (252.406 us; speedup 1.0000x reference)
//
#include <hip/hip_runtime.h>
#include <stdint.h>

typedef unsigned short u16;
typedef __attribute__((ext_vector_type(8))) short short8;
typedef __attribute__((ext_vector_type(4))) float floatx4;
typedef __attribute__((ext_vector_type(2))) float floatx2;

#define K_DIM 1024
#define N_DIM 1024
#define BM 64
#define BK 32
#define NCHUNK (K_DIM / BK)

__device__ __forceinline__ u16 f2b(float f) {
    union { float f; uint32_t i; } v; v.f = f;
    uint32_t u = v.i;
    return (u16)((u + 0x7FFFu + ((u >> 16) & 1u)) >> 16);   // RNE fp32->bf16
}
__device__ __forceinline__ float b2f(u16 u) {
    union { uint32_t i; float f; } v; v.i = ((uint32_t)u) << 16; return v.f;
}

// ---------- kernel 1: W fp32 -> bf16 into workspace (runs every launch) ----------
__global__ __launch_bounds__(256) void convert_w_kernel(const float* __restrict__ w,
                                                        u16* __restrict__ wbf) {
    int idx = (blockIdx.x * 256 + threadIdx.x) * 8;
    floatx4 a = *(const floatx4*)(w + idx);
    floatx4 b = *(const floatx4*)(w + idx + 4);
    short8 o;
    o[0] = (short)f2b(a[0]); o[1] = (short)f2b(a[1]);
    o[2] = (short)f2b(a[2]); o[3] = (short)f2b(a[3]);
    o[4] = (short)f2b(b[0]); o[5] = (short)f2b(b[1]);
    o[6] = (short)f2b(b[2]); o[7] = (short)f2b(b[3]);
    *(short8*)(wbf + idx) = o;
}

// ---------- kernel 2: fused GEMM + bias + LayerNorm + (ln+y)*y ----------
__global__ __launch_bounds__(1024) void fused_gemm_ln_kernel(
    const float* __restrict__ x, const float* __restrict__ y,
    const u16* __restrict__ wbf, const float* __restrict__ bias,
    const float* __restrict__ gamma, const float* __restrict__ beta,
    float* __restrict__ out)
{
    __shared__ __align__(16) u16 lds_a[2][BM * BK];   // 2 x 4KB bf16 A tiles, swizzled
    __shared__ __align__(16) u16 zbuf[16 * 1024];     // 32KB bf16 transpose buffer
    __shared__ float ls_sum[64];
    __shared__ float ls_sum2[64];
    __shared__ float ls_mean[64];
    __shared__ float ls_rs[64];

    const int tid  = threadIdx.x;
    const int lane = tid & 63;
    const int wv   = tid >> 6;            // 0..15
    const int q    = lane >> 4;           // quarter-wave id
    const int row0 = blockIdx.x * BM;

    if (tid < 64) { ls_sum[tid] = 0.0f; ls_sum2[tid] = 0.0f; }

    // ---- A staging (all 1024 threads, 2 fp32 each per chunk) ----
    // element (sr, sk..sk+1) -> LDS byte sr*64 + qs*16 + (sk&7)*2,
    // qs = (sk>>3) ^ ((sr>>1)&3)   (XOR swizzle, matches frag reads)
    const int sr = tid >> 4;              // 0..63
    const int sk = (tid & 15) << 1;       // even 0..30
    const float* s_src = x + (size_t)(row0 + sr) * K_DIM + sk;
    const int s_qs  = (sk >> 3) ^ ((sr >> 1) & 3);
    const int s_off = sr * 64 + s_qs * 16 + (sk & 7) * 2;

    // ---- B fragment base (bf16 W in workspace; direct from global/L2) ----
    const u16* wrow = wbf + (size_t)((wv << 6) + (lane & 15)) * K_DIM + (q << 3);

    // ---- A fragment LDS byte offsets ----
    int a_off[4];
#pragma unroll
    for (int mi = 0; mi < 4; ++mi) {
        int r  = (mi << 4) + (lane & 15);
        int qs = q ^ ((r >> 1) & 3);
        a_off[mi] = r * (BK * 2) + qs * 16;
    }

    floatx4 acc[4][4];
#pragma unroll
    for (int mi = 0; mi < 4; ++mi)
#pragma unroll
        for (int ni = 0; ni < 4; ++ni)
            acc[mi][ni] = (floatx4){0.0f, 0.0f, 0.0f, 0.0f};

    // prologue: stage chunk 0 into buffer 0
    {
        floatx2 v = *(const floatx2*)(s_src);
        uint32_t p = (uint32_t)f2b(v[0]) | ((uint32_t)f2b(v[1]) << 16);
        *(uint32_t*)((char*)(&lds_a[0][0]) + s_off) = p;
    }

    for (int kc = 0; kc < NCHUNK; ++kc) {
        const int cur = kc & 1;
        const bool pf = (kc + 1 < NCHUNK);
        floatx2 vn;
        if (pf) vn = *(const floatx2*)(s_src + (kc + 1) * BK);  // global->VGPR prefetch

        __syncthreads();                   // buf[cur] staged & prior reads done

        short8 bfrag[4];
        const u16* wp = wrow + kc * BK;
#pragma unroll
        for (int ni = 0; ni < 4; ++ni)
            bfrag[ni] = *(const short8*)(wp + ni * (16 * K_DIM));

        short8 afrag[4];
        const char* abase = (const char*)(&lds_a[cur][0]);
#pragma unroll
        for (int mi = 0; mi < 4; ++mi)
            afrag[mi] = *(const short8*)(abase + a_off[mi]);

#pragma unroll
        for (int mi = 0; mi < 4; ++mi)
#pragma unroll
            for (int ni = 0; ni < 4; ++ni)
                acc[mi][ni] = __builtin_amdgcn_mfma_f32_16x16x32_bf16(
                    afrag[mi], bfrag[ni], acc[mi][ni], 0, 0, 0);

        if (pf) {                          // convert + stage into other buffer
            uint32_t p = (uint32_t)f2b(vn[0]) | ((uint32_t)f2b(vn[1]) << 16);
            *(uint32_t*)((char*)(&lds_a[cur ^ 1][0]) + s_off) = p;
        }
    }

    // ---- epilogue: bias (fp32) ----
    float bias_v[4];
#pragma unroll
    for (int ni = 0; ni < 4; ++ni)
        bias_v[ni] = bias[(wv << 6) + (ni << 4) + (lane & 15)];
#pragma unroll
    for (int mi = 0; mi < 4; ++mi)
#pragma unroll
        for (int ni = 0; ni < 4; ++ni)
#pragma unroll
            for (int r = 0; r < 4; ++r)
                acc[mi][ni][r] += bias_v[ni];

    // ---- row stats: in-wave 64-col reduce, then LDS float atomics ----
#pragma unroll
    for (int mi = 0; mi < 4; ++mi)
#pragma unroll
        for (int r = 0; r < 4; ++r) {
            float s = 0.0f, s2 = 0.0f;
#pragma unroll
            for (int ni = 0; ni < 4; ++ni) {
                float v = acc[mi][ni][r];
                s += v; s2 += v * v;
            }
#pragma unroll
            for (int m = 1; m < 16; m <<= 1) {
                s  += __shfl_xor(s,  m, 64);
                s2 += __shfl_xor(s2, m, 64);
            }
            if ((lane & 15) == 0) {
                int rl = (mi << 4) + (q << 2) + r;       // C row = q*4 + r
                atomicAdd(&ls_sum[rl], s);
                atomicAdd(&ls_sum2[rl], s2);
            }
        }

    __syncthreads();
    if (tid < 64) {
        float mean = ls_sum[tid] * (1.0f / 1024.0f);
        float var  = ls_sum2[tid] * (1.0f / 1024.0f) - mean * mean;
        ls_mean[tid] = mean;
        ls_rs[tid]   = rsqrtf(var + 1e-5f);
    }

    // ---- per 16-row slice: LDS transpose (bf16), coalesced fp32 LN+res+mul ----
    for (int mi = 0; mi < 4; ++mi) {
#pragma unroll
        for (int ni = 0; ni < 4; ++ni)
#pragma unroll
            for (int r = 0; r < 4; ++r) {
                int lr   = (q << 2) + r;                          // local row 0..15
                int lin  = (((wv << 6) + (ni << 4) + (lane & 15)) << 1);
                int phys = lr * 2048 + (lin ^ (q << 5));          // swizzled
                *(u16*)((char*)zbuf + phys) = f2b(acc[mi][ni][r]);
            }
        __syncthreads();
#pragma unroll
        for (int it = 0; it < 2; ++it) {
            int row  = (tid >> 7) + (it << 3);                    // 0..15
            int c8   = tid & 127;                                 // 16B chunk id
            int phys = row * 2048 + ((c8 << 4) ^ (((row >> 2) & 3) << 5));
            short8 z8 = *(const short8*)((const char*)zbuf + phys);
            int grow  = row0 + (mi << 4) + row;
            float mean = ls_mean[(mi << 4) + row];
            float rs   = ls_rs[(mi << 4) + row];
            const float* yp = y     + (size_t)grow * N_DIM + c8 * 8;
            const float* gp = gamma + c8 * 8;
            const float* bp = beta  + c8 * 8;
            float*       op = out   + (size_t)grow * N_DIM + c8 * 8;
            floatx4 y0 = *(const floatx4*)(yp);
            floatx4 y1 = *(const floatx4*)(yp + 4);
            floatx4 g0 = *(const floatx4*)(gp);
            floatx4 g1 = *(const floatx4*)(gp + 4);
            floatx4 b0 = *(const floatx4*)(bp);
            floatx4 b1 = *(const floatx4*)(bp + 4);
            floatx4 o0, o1;
#pragma unroll
            for (int e = 0; e < 4; ++e) {
                float zv = b2f((u16)z8[e]);
                o0[e] = ((zv - mean) * rs * g0[e] + b0[e] + y0[e]) * y0[e];
            }
#pragma unroll
            for (int e = 0; e < 4; ++e) {
                float zv = b2f((u16)z8[e + 4]);
                o1[e] = ((zv - mean) * rs * g1[e] + b1[e] + y1[e]) * y1[e];
            }
            *(floatx4*)(op)     = o0;
            *(floatx4*)(op + 4) = o1;
        }
        __syncthreads();
    }
}

extern "C" void kernel_launch(void* const* d_in, const int* in_sizes, int n_in,
                              void* d_out, int out_size, void* d_ws, size_t ws_size,
                              hipStream_t stream) {
    const float* x     = (const float*)d_in[0];
    const float* y     = (const float*)d_in[1];
    const float* wgt   = (const float*)d_in[2];
    const float* bias  = (const float*)d_in[3];
    const float* gamma = (const float*)d_in[4];
    const float* beta  = (const float*)d_in[5];
    float* out = (float*)d_out;
    u16* wbf = (u16*)d_ws;                               // 2MB bf16 W

    const int wElems = in_sizes[2];                      // 1048576
    convert_w_kernel<<<wElems / (256 * 8), 256, 0, stream>>>(wgt, wbf);

    const int M = in_sizes[0] / K_DIM;                   // 16384
    fused_gemm_ln_kernel<<<M / BM, 1024, 0, stream>>>(x, y, wbf, bias, gamma, beta, out);
}

// Round 4
// 229.093 us; speedup vs baseline: 1.1018x; 1.1018x over previous
//
#include <hip/hip_runtime.h>
#include <stdint.h>

typedef unsigned short u16;
typedef __attribute__((ext_vector_type(8))) short short8;
typedef __attribute__((ext_vector_type(4))) float floatx4;
typedef __attribute__((ext_vector_type(2))) float floatx2;

#define K_DIM 1024
#define N_DIM 1024
#define BM 64
#define BK 32
#define NCHUNK (K_DIM / BK)

__device__ __forceinline__ u16 f2b(float f) {
    union { float f; uint32_t i; } v; v.f = f;
    uint32_t u = v.i;
    return (u16)((u + 0x7FFFu + ((u >> 16) & 1u)) >> 16);   // RNE fp32->bf16
}
__device__ __forceinline__ float b2f(u16 u) {
    union { uint32_t i; float f; } v; v.i = ((uint32_t)u) << 16; return v.f;
}

// ---------- kernel 1: W fp32 -> bf16, packed in MFMA-fragment order ----------
// packed[((tile*32 + kc)*64 + lane)*8 + j] = bf16(W[tile*16 + (lane&15)][kc*32 + (lane>>4)*8 + j])
// Needs 64 tiles * 32 kc * 64 lanes = 131072 threads -> 512 blocks of 256.
// (Round-3 bug: launched 256 blocks, packing only tiles 0..31.)
__global__ __launch_bounds__(256) void pack_w_kernel(const float* __restrict__ w,
                                                     u16* __restrict__ wpk) {
    int gid  = blockIdx.x * 256 + threadIdx.x;   // 0..131071: (tile,kc,lane)
    int lane = gid & 63;
    int kc   = (gid >> 6) & 31;
    int tile = gid >> 11;                        // 0..63
    int n = tile * 16 + (lane & 15);
    int k = kc * 32 + (lane >> 4) * 8;
    const float* src = w + (size_t)n * K_DIM + k;
    floatx4 a = *(const floatx4*)(src);
    floatx4 b = *(const floatx4*)(src + 4);
    short8 o;
    o[0] = (short)f2b(a[0]); o[1] = (short)f2b(a[1]);
    o[2] = (short)f2b(a[2]); o[3] = (short)f2b(a[3]);
    o[4] = (short)f2b(b[0]); o[5] = (short)f2b(b[1]);
    o[6] = (short)f2b(b[2]); o[7] = (short)f2b(b[3]);
    *(short8*)(wpk + (size_t)gid * 8) = o;
}

// ---------- kernel 2: fused GEMM + bias + LayerNorm + (ln+y)*y ----------
__global__ __launch_bounds__(1024) void fused_gemm_ln_kernel(
    const float* __restrict__ x, const float* __restrict__ y,
    const u16* __restrict__ wpk, const float* __restrict__ bias,
    const float* __restrict__ gamma, const float* __restrict__ beta,
    float* __restrict__ out)
{
    __shared__ __align__(16) u16 lds_a[2][BM * BK];   // 2 x 4KB bf16 A tiles, swizzled
    __shared__ __align__(16) u16 zbuf[16 * 1024];     // 32KB bf16 transpose buffer
    __shared__ float ls_sum[64];
    __shared__ float ls_sum2[64];
    __shared__ float ls_mean[64];
    __shared__ float ls_rs[64];

    const int tid  = threadIdx.x;
    const int lane = tid & 63;
    const int wv   = tid >> 6;            // 0..15
    const int q    = lane >> 4;           // quarter-wave id
    const int row0 = blockIdx.x * BM;

    if (tid < 64) { ls_sum[tid] = 0.0f; ls_sum2[tid] = 0.0f; }

    // ---- A staging (all 1024 threads, 2 fp32 each per chunk) ----
    const int sr = tid >> 4;              // 0..63
    const int sk = (tid & 15) << 1;       // even 0..30
    const float* s_src = x + (size_t)(row0 + sr) * K_DIM + sk;
    const int s_qs  = (sk >> 3) ^ ((sr >> 1) & 3);
    const int s_off = sr * 64 + s_qs * 16 + (sk & 7) * 2;

    // ---- B: packed fragment base (contiguous 1KB per frag per wave) ----
    const u16* bp = wpk + (size_t)wv * 65536 + lane * 8;
    // frag (ni, kc) at bp + ni*16384 + kc*512   (elements)

    // ---- A fragment LDS base offset (mi-invariant swizzle) ----
    const int a_base = (lane & 15) * 64 + (q ^ (((lane & 15) >> 1) & 3)) * 16;

    floatx4 acc[4][4];
#pragma unroll
    for (int mi = 0; mi < 4; ++mi)
#pragma unroll
        for (int ni = 0; ni < 4; ++ni)
            acc[mi][ni] = (floatx4){0.0f, 0.0f, 0.0f, 0.0f};

    // ---- prologue: stage A chunk0, load B chunk0 ----
    {
        floatx2 v = *(const floatx2*)(s_src);
        uint32_t p = (uint32_t)f2b(v[0]) | ((uint32_t)f2b(v[1]) << 16);
        *(uint32_t*)((char*)(&lds_a[0][0]) + s_off) = p;
    }
    short8 bfr[2][4];
#pragma unroll
    for (int ni = 0; ni < 4; ++ni)
        bfr[0][ni] = *(const short8*)(bp + ni * 16384);

#pragma unroll 2
    for (int kc = 0; kc < NCHUNK; ++kc) {
        const int cur = kc & 1;
        const bool pf = (kc + 1 < NCHUNK);

        __syncthreads();   // staging of buf[cur] visible; prefetches drained (complete)

        // A frags for this chunk from LDS
        short8 afrag[4];
        const char* ab = (const char*)(&lds_a[cur][0]);
#pragma unroll
        for (int mi = 0; mi < 4; ++mi)
            afrag[mi] = *(const short8*)(ab + a_base + mi * 1024);

        // prefetch NEXT chunk (global) — lands during the MFMA phase below
        floatx2 vn;
        if (pf) {
#pragma unroll
            for (int ni = 0; ni < 4; ++ni)
                bfr[cur ^ 1][ni] = *(const short8*)(bp + ni * 16384 + (kc + 1) * 512);
            vn = *(const floatx2*)(s_src + (kc + 1) * BK);
        }

#pragma unroll
        for (int mi = 0; mi < 4; ++mi)
#pragma unroll
            for (int ni = 0; ni < 4; ++ni)
                acc[mi][ni] = __builtin_amdgcn_mfma_f32_16x16x32_bf16(
                    afrag[mi], bfr[cur][ni], acc[mi][ni], 0, 0, 0);

        if (pf) {   // convert + stage next A tile into other buffer
            uint32_t p = (uint32_t)f2b(vn[0]) | ((uint32_t)f2b(vn[1]) << 16);
            *(uint32_t*)((char*)(&lds_a[cur ^ 1][0]) + s_off) = p;
        }
    }

    // ---- epilogue: bias (fp32) ----
    float bias_v[4];
#pragma unroll
    for (int ni = 0; ni < 4; ++ni)
        bias_v[ni] = bias[(wv << 6) + (ni << 4) + (lane & 15)];
#pragma unroll
    for (int mi = 0; mi < 4; ++mi)
#pragma unroll
        for (int ni = 0; ni < 4; ++ni)
#pragma unroll
            for (int r = 0; r < 4; ++r)
                acc[mi][ni][r] += bias_v[ni];

    // ---- row stats: in-wave 64-col reduce, then LDS float atomics ----
#pragma unroll
    for (int mi = 0; mi < 4; ++mi)
#pragma unroll
        for (int r = 0; r < 4; ++r) {
            float s = 0.0f, s2 = 0.0f;
#pragma unroll
            for (int ni = 0; ni < 4; ++ni) {
                float v = acc[mi][ni][r];
                s += v; s2 += v * v;
            }
#pragma unroll
            for (int m = 1; m < 16; m <<= 1) {
                s  += __shfl_xor(s,  m, 64);
                s2 += __shfl_xor(s2, m, 64);
            }
            if ((lane & 15) == 0) {
                int rl = (mi << 4) + (q << 2) + r;       // C row = q*4 + r
                atomicAdd(&ls_sum[rl], s);
                atomicAdd(&ls_sum2[rl], s2);
            }
        }

    __syncthreads();
    if (tid < 64) {
        float mean = ls_sum[tid] * (1.0f / 1024.0f);
        float var  = ls_sum2[tid] * (1.0f / 1024.0f) - mean * mean;
        ls_mean[tid] = mean;
        ls_rs[tid]   = rsqrtf(var + 1e-5f);
    }

    // ---- per 16-row slice: LDS transpose (bf16), coalesced fp32 LN+res+mul ----
    for (int mi = 0; mi < 4; ++mi) {
#pragma unroll
        for (int ni = 0; ni < 4; ++ni)
#pragma unroll
            for (int r = 0; r < 4; ++r) {
                int lr   = (q << 2) + r;                          // local row 0..15
                int lin  = (((wv << 6) + (ni << 4) + (lane & 15)) << 1);
                int phys = lr * 2048 + (lin ^ (q << 5));          // swizzled
                *(u16*)((char*)zbuf + phys) = f2b(acc[mi][ni][r]);
            }
        __syncthreads();
#pragma unroll
        for (int it = 0; it < 2; ++it) {
            int row  = (tid >> 7) + (it << 3);                    // 0..15
            int c8   = tid & 127;                                 // 16B chunk id
            int phys = row * 2048 + ((c8 << 4) ^ (((row >> 2) & 3) << 5));
            short8 z8 = *(const short8*)((const char*)zbuf + phys);
            int grow  = row0 + (mi << 4) + row;
            float mean = ls_mean[(mi << 4) + row];
            float rs   = ls_rs[(mi << 4) + row];
            const float* yp = y     + (size_t)grow * N_DIM + c8 * 8;
            const float* gp = gamma + c8 * 8;
            const float* bpv = beta + c8 * 8;
            float*       op = out   + (size_t)grow * N_DIM + c8 * 8;
            floatx4 y0 = *(const floatx4*)(yp);
            floatx4 y1 = *(const floatx4*)(yp + 4);
            floatx4 g0 = *(const floatx4*)(gp);
            floatx4 g1 = *(const floatx4*)(gp + 4);
            floatx4 b0 = *(const floatx4*)(bpv);
            floatx4 b1 = *(const floatx4*)(bpv + 4);
            floatx4 o0, o1;
#pragma unroll
            for (int e = 0; e < 4; ++e) {
                float zv = b2f((u16)z8[e]);
                o0[e] = ((zv - mean) * rs * g0[e] + b0[e] + y0[e]) * y0[e];
            }
#pragma unroll
            for (int e = 0; e < 4; ++e) {
                float zv = b2f((u16)z8[e + 4]);
                o1[e] = ((zv - mean) * rs * g1[e] + b1[e] + y1[e]) * y1[e];
            }
            *(floatx4*)(op)     = o0;
            *(floatx4*)(op + 4) = o1;
        }
        __syncthreads();
    }
}

extern "C" void kernel_launch(void* const* d_in, const int* in_sizes, int n_in,
                              void* d_out, int out_size, void* d_ws, size_t ws_size,
                              hipStream_t stream) {
    const float* x     = (const float*)d_in[0];
    const float* y     = (const float*)d_in[1];
    const float* wgt   = (const float*)d_in[2];
    const float* bias  = (const float*)d_in[3];
    const float* gamma = (const float*)d_in[4];
    const float* beta  = (const float*)d_in[5];
    float* out = (float*)d_out;
    u16* wpk = (u16*)d_ws;                               // 2MB packed bf16 W

    pack_w_kernel<<<512, 256, 0, stream>>>(wgt, wpk);    // 131072 threads: full coverage

    const int M = in_sizes[0] / K_DIM;                   // 16384
    fused_gemm_ln_kernel<<<M / BM, 1024, 0, stream>>>(x, y, wpk, bias, gamma, beta, out);
}